// Round 1
// baseline (127.687 us; speedup 1.0000x reference)
//
#include <hip/hip_runtime.h>

#define NGT   32
#define MAXA  2048          // n_ac is 1384 for this problem; packing supports < 4096
#define EPSF  1e-5f

__global__ __launch_bounds__(256) void rpn_kernel(
    const float* __restrict__ bx_gt,     // (B, 32, 4)
    const float* __restrict__ ac_val,    // (n_ac, 4)
    const float* __restrict__ rand_pos,  // (B, n_ac)
    const float* __restrict__ rand_neg,  // (B, n_ac)
    float* __restrict__ out,             // (B, n_ac, 10)
    int n_ac)
{
    #pragma clang fp contract(off)   // match numpy rounding: no cross-statement FMA

    const int b   = blockIdx.x;
    const int tid = threadIdx.x;

    __shared__ float s_gt[NGT * 4];
    __shared__ float s_agt[NGT];
    __shared__ int   s_colkey[NGT];            // (v<<12) | (4095 - a): max => max v, ties -> min a
    __shared__ unsigned short s_iou[MAXA];     // per-anchor max int iou (<= 10000)
    __shared__ unsigned char  s_bgt[MAXA];     // per-anchor best gt index (< 32)
    __shared__ unsigned char  s_flag[MAXA];    // phase B: pos_gtac; phase C: 1=pos 2=neg 0=ignore
    __shared__ int   s_cnt[2];                 // fg count, bg count

    if (tid < NGT * 4) s_gt[tid] = bx_gt[(size_t)b * NGT * 4 + tid];
    if (tid < NGT)     s_colkey[tid] = 0;
    if (tid < 2)       s_cnt[tid] = 0;
    for (int a = tid; a < n_ac; a += 256) s_flag[a] = 0;
    __syncthreads();
    if (tid < NGT) {
        float g0 = s_gt[tid*4+0], g1 = s_gt[tid*4+1];
        float g2 = s_gt[tid*4+2], g3 = s_gt[tid*4+3];
        s_agt[tid] = (g2 - g0) * (g3 - g1);
    }
    __syncthreads();

    // ---- Phase A: IOU matrix; row max/argmax; per-thread column keys ----
    int ckey[NGT];
    #pragma unroll
    for (int g = 0; g < NGT; ++g) ckey[g] = 0;

    for (int a = tid; a < n_ac; a += 256) {
        const float4 av = ((const float4*)ac_val)[a];
        const float a0 = av.x, a1 = av.y, a2 = av.z, a3 = av.w;
        const float area_ac = (a2 - a0) * (a3 - a1);
        int vmax = -1, bgt = 0;
        #pragma unroll
        for (int g = 0; g < NGT; ++g) {
            float g0 = s_gt[g*4+0], g1 = s_gt[g*4+1];
            float g2 = s_gt[g*4+2], g3 = s_gt[g*4+3];
            float ih = fmaxf(fminf(a2, g2) - fmaxf(a0, g0), 0.0f);
            float iw = fmaxf(fminf(a3, g3) - fmaxf(a1, g1), 0.0f);
            float inter = ih * iw;
            float uni = area_ac + s_agt[g] - inter;   // same assoc order as numpy
            float iou = inter / (uni + EPSF);
            int v = (int)(iou * 10000.0f);            // trunc toward zero, like astype(int32)
            if (v > vmax) { vmax = v; bgt = g; }      // strict > : first-index tie-break
            int key = (v << 12) | (4095 - a);
            ckey[g] = max(ckey[g], key);
        }
        s_iou[a] = (unsigned short)vmax;
        s_bgt[a] = (unsigned char)bgt;
    }

    // wave-reduce column keys, then one atomic per wave per gt
    #pragma unroll
    for (int g = 0; g < NGT; ++g) {
        int k = ckey[g];
        #pragma unroll
        for (int off = 32; off >= 1; off >>= 1)
            k = max(k, __shfl_xor(k, off, 64));
        if ((tid & 63) == 0) atomicMax(&s_colkey[g], k);
    }
    __syncthreads();

    // ---- Phase B: mark pos_gtac anchors ----
    if (tid < NGT) {
        int key = s_colkey[tid];
        int v = key >> 12;
        if (v >= 100) {                       // POS_TH_GTAC = int(1e4*0.01)
            int a = 4095 - (key & 4095);
            s_flag[a] = 1;                    // same-value byte stores: benign
        }
    }
    __syncthreads();

    // ---- Phase C: classify + count ----
    int cf = 0, cb = 0;
    for (int a = tid; a < n_ac; a += 256) {
        int vmax = s_iou[a];
        int f;
        if (vmax >= 5000 || s_flag[a]) f = 1;         // pos
        else if (vmax < 3000)          f = 2;         // neg
        else                           f = 0;
        s_flag[a] = (unsigned char)f;
        cf += (f == 1);
        cb += (f == 2);
    }
    #pragma unroll
    for (int off = 32; off >= 1; off >>= 1) {
        cf += __shfl_xor(cf, off, 64);
        cb += __shfl_xor(cb, off, 64);
    }
    if ((tid & 63) == 0) { atomicAdd(&s_cnt[0], cf); atomicAdd(&s_cnt[1], cb); }
    __syncthreads();

    const float th_pos = 128.0f / ((float)s_cnt[0] + 1e-6f);
    const float th_neg = 128.0f / ((float)s_cnt[1] + 1e-6f);

    // ---- Phase D: write outputs ----
    const float* rp = rand_pos + (size_t)b * n_ac;
    const float* rn = rand_neg + (size_t)b * n_ac;
    for (int a = tid; a < n_ac; a += 256) {
        const float4 av = ((const float4*)ac_val)[a];
        const float a0 = av.x, a1 = av.y, a2 = av.z, a3 = av.w;
        const int f = s_flag[a];
        float o0, o1, o2, o3, o4, o5, o6, o7;
        if (f == 1) {
            int g = s_bgt[a];
            float g0 = s_gt[g*4+0], g1 = s_gt[g*4+1];
            float g2 = s_gt[g*4+2], g3 = s_gt[g*4+3];
            o0 = g0; o1 = g1; o2 = g2; o3 = g3;
            float hr = fmaxf(a2 - a0, EPSF);
            float wr = fmaxf(a3 - a1, EPSF);
            float ycr = a0 + 0.5f * (a2 - a0);
            float xcr = a1 + 0.5f * (a3 - a1);
            float hl = g2 - g0, wl = g3 - g1;
            float ycl = g0 + 0.5f * hl;
            float xcl = g1 + 0.5f * wl;
            o4 = fminf(fmaxf((xcl - xcr) / wr, -10.0f), 10.0f);
            o5 = fminf(fmaxf((ycl - ycr) / hr, -10.0f), 10.0f);
            o6 = fminf(fmaxf(logf(wl / wr), -10.0f), 10.0f);
            o7 = fminf(fmaxf(logf(hl / hr), -10.0f), 10.0f);
        } else {
            float t = (f == 2) ? -2.0f : -1.0f;
            o0 = o1 = o2 = o3 = t;
            o4 = o5 = o6 = o7 = 0.0f;        // bx_safe == anchor => delta exactly 0
        }
        float o8 = (f == 1 && rp[a] < th_pos) ? 1.0f : 0.0f;
        float o9 = (f == 2 && rn[a] < th_neg) ? 1.0f : 0.0f;

        float* dst = out + ((size_t)b * n_ac + a) * 10;
        dst[0] = o0; dst[1] = o1; dst[2] = o2; dst[3] = o3;
        dst[4] = o4; dst[5] = o5; dst[6] = o6; dst[7] = o7;
        dst[8] = o8; dst[9] = o9;
    }
}

extern "C" void kernel_launch(void* const* d_in, const int* in_sizes, int n_in,
                              void* d_out, int out_size, void* d_ws, size_t ws_size,
                              hipStream_t stream) {
    const float* bx_gt    = (const float*)d_in[0];
    const float* ac_val   = (const float*)d_in[1];
    const float* rand_pos = (const float*)d_in[2];
    const float* rand_neg = (const float*)d_in[3];
    float* out = (float*)d_out;

    const int n_ac = in_sizes[1] / 4;          // (n_ac, 4)
    const int B    = in_sizes[2] / n_ac;       // rand_pos is (B, n_ac)

    rpn_kernel<<<B, 256, 0, stream>>>(bx_gt, ac_val, rand_pos, rand_neg, out, n_ac);
}

// Round 2
// 120.309 us; speedup vs baseline: 1.0613x; 1.0613x over previous
//
#include <hip/hip_runtime.h>

#define NGT   32
#define EPSF  1e-5f
#define GTAC_BIT (1 << 20)

// ---------------- Kernel 1: IOU + row stats + column keys + partial counts ----
__global__ __launch_bounds__(256) void rpn_k1(
    const float* __restrict__ bx_gt,   // (B, 32, 4)
    const float* __restrict__ ac_val,  // (n_ac, 4)
    int* __restrict__ pack,            // (B, n_ac)  (vmax<<5)|bgt
    int* __restrict__ colkey,          // (B, 32)    atomicMax target (poison is negative)
    int* __restrict__ partial,         // (B, n_chunk, 2)
    int n_ac)
{
    #pragma clang fp contract(off)   // match numpy rounding: no cross-statement FMA
    const int b = blockIdx.y, chunk = blockIdx.x, tid = threadIdx.x;
    const int w = tid >> 6, lane = tid & 63;

    __shared__ float s_gt[NGT * 4];
    __shared__ float s_agt[NGT];
    __shared__ int   s_wk[NGT * 4];   // per-wave column-key maxes
    __shared__ int   s_c[8];          // per-wave fg/bg partials

    if (tid < NGT * 4) s_gt[tid] = bx_gt[(size_t)b * NGT * 4 + tid];
    __syncthreads();
    if (tid < NGT) {
        float g0 = s_gt[tid*4+0], g1 = s_gt[tid*4+1];
        float g2 = s_gt[tid*4+2], g3 = s_gt[tid*4+3];
        s_agt[tid] = (g2 - g0) * (g3 - g1);
    }
    __syncthreads();

    const int a = chunk * 256 + tid;
    const bool active = (a < n_ac);
    float a0 = 0.f, a1 = 0.f, a2 = 0.f, a3 = 0.f, area = 0.f;
    if (active) {
        float4 av = ((const float4*)ac_val)[a];
        a0 = av.x; a1 = av.y; a2 = av.z; a3 = av.w;
        area = (a2 - a0) * (a3 - a1);
    }

    int vmax = -1, bgt = 0;
    #pragma unroll
    for (int g = 0; g < NGT; ++g) {
        float g0 = s_gt[g*4+0], g1 = s_gt[g*4+1];
        float g2 = s_gt[g*4+2], g3 = s_gt[g*4+3];
        float ih = fmaxf(fminf(a2, g2) - fmaxf(a0, g0), 0.0f);
        float iw = fmaxf(fminf(a3, g3) - fmaxf(a1, g1), 0.0f);
        float inter = ih * iw;
        float uni = area + s_agt[g] - inter;       // same assoc order as numpy
        float iou = inter / (uni + EPSF);
        int v = (int)(iou * 10000.0f);             // trunc toward zero == astype(int32)
        if (active && v > vmax) { vmax = v; bgt = g; }   // strict > : first-index ties
        int key = active ? ((v << 12) | (4095 - a)) : 0; // max => max v, ties -> min a
        #pragma unroll
        for (int off = 32; off >= 1; off >>= 1)
            key = max(key, __shfl_xor(key, off, 64));
        if (lane == 0) s_wk[g*4 + w] = key;
    }

    if (active) pack[(size_t)b * n_ac + a] = (vmax << 5) | bgt;

    int cf = (active && vmax >= 5000) ? 1 : 0;
    int cb = (active && vmax < 3000 && vmax >= 0) ? 1 : 0;
    #pragma unroll
    for (int off = 32; off >= 1; off >>= 1) {
        cf += __shfl_xor(cf, off, 64);
        cb += __shfl_xor(cb, off, 64);
    }
    if (lane == 0) { s_c[w*2] = cf; s_c[w*2+1] = cb; }
    __syncthreads();

    if (tid < NGT) {
        int k = max(max(s_wk[tid*4+0], s_wk[tid*4+1]),
                    max(s_wk[tid*4+2], s_wk[tid*4+3]));
        atomicMax(&colkey[b * NGT + tid], k);   // signed: 0xAAAAAAAA poison always loses
    }
    if (tid == 0) {
        partial[(b * gridDim.x + chunk) * 2 + 0] = s_c[0] + s_c[2] + s_c[4] + s_c[6];
        partial[(b * gridDim.x + chunk) * 2 + 1] = s_c[1] + s_c[3] + s_c[5] + s_c[7];
    }
}

// ---------------- Kernel 2: finalize counts, mark gtac anchors, thresholds ----
__global__ __launch_bounds__(64) void rpn_k2(
    int* __restrict__ pack,
    const int* __restrict__ colkey,
    const int* __restrict__ partial,
    float* __restrict__ th,            // (B, 2)
    int n_ac, int n_chunk)
{
    const int b = blockIdx.x, tid = threadIdx.x;   // one wave per batch row

    int pf = 0, pb = 0;
    if (tid < n_chunk) {
        pf = partial[(b * n_chunk + tid) * 2 + 0];
        pb = partial[(b * n_chunk + tid) * 2 + 1];
    }
    #pragma unroll
    for (int off = 32; off >= 1; off >>= 1) {
        pf += __shfl_xor(pf, off, 64);
        pb += __shfl_xor(pb, off, 64);
    }

    int valid = 0, a = 0;
    if (tid < NGT) {
        int key = colkey[b * NGT + tid];
        int v = key >> 12;
        a = 4095 - (key & 4095);
        valid = (v >= 100);               // POS_TH_GTAC
    }
    // dedupe: count each distinct gtac anchor once (first occurrence)
    int av = valid ? a : (0x10000 + tid); // unique sentinel for invalid lanes
    bool dup = false;
    for (int gp = 0; gp < NGT; ++gp) {
        int o = __shfl(av, gp, 64);
        if (gp < tid && o == av) dup = true;
    }
    bool contrib = valid && !dup;
    int rm = 0x7FFF;
    if (contrib) rm = pack[(size_t)b * n_ac + a] >> 5;  // single wave: loads precede atomicOr
    unsigned long long m1 = __ballot(contrib && rm < 5000); // gtac-only positives
    unsigned long long m2 = __ballot(contrib && rm < 3000); // were counted as neg, now pos

    if (contrib) atomicOr(&pack[(size_t)b * n_ac + a], GTAC_BIT);

    if (tid == 0) {
        int cf = pf + __popcll(m1);
        int cb = pb - __popcll(m2);
        th[b*2 + 0] = 128.0f / ((float)cf + 1e-6f);
        th[b*2 + 1] = 128.0f / ((float)cb + 1e-6f);
    }
}

// ---------------- Kernel 3: per-anchor epilogue + output write ----------------
__global__ __launch_bounds__(256) void rpn_k3(
    const float* __restrict__ bx_gt,
    const float* __restrict__ ac_val,
    const float* __restrict__ rand_pos,
    const float* __restrict__ rand_neg,
    const int* __restrict__ pack,
    const float* __restrict__ th,
    float* __restrict__ out,           // (B, n_ac, 10)
    int n_ac)
{
    #pragma clang fp contract(off)
    const int b = blockIdx.y, chunk = blockIdx.x, tid = threadIdx.x;
    __shared__ float s_gt[NGT * 4];
    if (tid < NGT * 4) s_gt[tid] = bx_gt[(size_t)b * NGT * 4 + tid];
    __syncthreads();

    const int a = chunk * 256 + tid;
    if (a >= n_ac) return;

    const float th_pos = th[b*2 + 0];
    const float th_neg = th[b*2 + 1];
    const int p = pack[(size_t)b * n_ac + a];
    const bool gtac = (p & GTAC_BIT) != 0;
    const int rm = (p >> 5) & 0x7FFF;   // masks out GTAC_BIT>>5 (bit 15); rm <= 10000
    const int bg = p & 31;
    const bool pos = (rm >= 5000) || gtac;
    const bool neg = !pos && (rm < 3000);

    const float4 av = ((const float4*)ac_val)[a];
    const float a0 = av.x, a1 = av.y, a2 = av.z, a3 = av.w;

    float o0, o1, o2, o3, o4, o5, o6, o7;
    if (pos) {
        float g0 = s_gt[bg*4+0], g1 = s_gt[bg*4+1];
        float g2 = s_gt[bg*4+2], g3 = s_gt[bg*4+3];
        o0 = g0; o1 = g1; o2 = g2; o3 = g3;
        float hr = fmaxf(a2 - a0, EPSF);
        float wr = fmaxf(a3 - a1, EPSF);
        float ycr = a0 + 0.5f * (a2 - a0);
        float xcr = a1 + 0.5f * (a3 - a1);
        float hl = g2 - g0, wl = g3 - g1;
        float ycl = g0 + 0.5f * hl;
        float xcl = g1 + 0.5f * wl;
        o4 = fminf(fmaxf((xcl - xcr) / wr, -10.0f), 10.0f);
        o5 = fminf(fmaxf((ycl - ycr) / hr, -10.0f), 10.0f);
        o6 = fminf(fmaxf(logf(wl / wr), -10.0f), 10.0f);
        o7 = fminf(fmaxf(logf(hl / hr), -10.0f), 10.0f);
    } else {
        float t = neg ? -2.0f : -1.0f;
        o0 = o1 = o2 = o3 = t;
        o4 = o5 = o6 = o7 = 0.0f;       // bx_safe == anchor => delta exactly 0
    }
    const float o8 = (pos && rand_pos[(size_t)b * n_ac + a] < th_pos) ? 1.0f : 0.0f;
    const float o9 = (neg && rand_neg[(size_t)b * n_ac + a] < th_neg) ? 1.0f : 0.0f;

    float* dst = out + ((size_t)b * n_ac + a) * 10;
    dst[0] = o0; dst[1] = o1; dst[2] = o2; dst[3] = o3;
    dst[4] = o4; dst[5] = o5; dst[6] = o6; dst[7] = o7;
    dst[8] = o8; dst[9] = o9;
}

extern "C" void kernel_launch(void* const* d_in, const int* in_sizes, int n_in,
                              void* d_out, int out_size, void* d_ws, size_t ws_size,
                              hipStream_t stream) {
    const float* bx_gt    = (const float*)d_in[0];
    const float* ac_val   = (const float*)d_in[1];
    const float* rand_pos = (const float*)d_in[2];
    const float* rand_neg = (const float*)d_in[3];
    float* out = (float*)d_out;

    const int n_ac    = in_sizes[1] / 4;     // (n_ac, 4)
    const int B       = in_sizes[2] / n_ac;  // rand_pos is (B, n_ac)
    const int n_chunk = (n_ac + 255) / 256;

    // workspace layout (ints): pack[B*n_ac] | colkey[B*32] | partial[B*n_chunk*2] | th (floats, B*2)
    int* pack    = (int*)d_ws;
    int* colkey  = pack + (size_t)B * n_ac;
    int* partial = colkey + (size_t)B * NGT;
    float* th    = (float*)(partial + (size_t)B * n_chunk * 2);

    rpn_k1<<<dim3(n_chunk, B), 256, 0, stream>>>(bx_gt, ac_val, pack, colkey, partial, n_ac);
    rpn_k2<<<B, 64, 0, stream>>>(pack, colkey, partial, th, n_ac, n_chunk);
    rpn_k3<<<dim3(n_chunk, B), 256, 0, stream>>>(bx_gt, ac_val, rand_pos, rand_neg,
                                                 pack, th, out, n_ac);
}

// Round 3
// 114.266 us; speedup vs baseline: 1.1175x; 1.0529x over previous
//
#include <hip/hip_runtime.h>

#define NGT   32
#define EPSF  1e-5f
#define GTAC_BIT (1 << 20)
#define APT   3            // anchors per thread in k1
#define K1SPAN (APT * 256) // anchors per k1 block

// ---------------- Kernel 1: IOU + row stats + column keys + partial counts ----
// pack[b][a] = (vmax<<5) | (31 - best_gt)   (strict-first-tie argmax over g)
__global__ __launch_bounds__(256) void rpn_k1(
    const float* __restrict__ bx_gt,   // (B, 32, 4)
    const float* __restrict__ ac_val,  // (n_ac, 4)
    int* __restrict__ pack,            // (B, n_ac)
    int* __restrict__ colkey,          // (B, 32) atomicMax target (poison negative)
    int* __restrict__ partial,         // (B, n_chunk, 2)
    int n_ac)
{
    #pragma clang fp contract(off)   // match numpy rounding: no cross-statement FMA
    const int b = blockIdx.y, chunk = blockIdx.x, tid = threadIdx.x;
    const int w = tid >> 6, lane = tid & 63;

    __shared__ int s_wk[NGT * 4];   // per-wave column-key maxes
    __shared__ int s_c[8];          // per-wave fg/bg partials

    // wave-uniform base for GT boxes -> scalar loads, no LDS
    const float4* __restrict__ gtp = (const float4*)(bx_gt + (size_t)b * NGT * 4);

    int ckey[NGT];
    #pragma unroll
    for (int g = 0; g < NGT; ++g) ckey[g] = 0;

    int cf = 0, cb = 0;

    for (int j = 0; j < APT; ++j) {
        const int a = chunk * K1SPAN + j * 256 + tid;
        const bool active = (a < n_ac);
        float a0 = 0.f, a1 = 0.f, a2 = 0.f, a3 = 0.f;
        if (active) {
            float4 av = ((const float4*)ac_val)[a];
            a0 = av.x; a1 = av.y; a2 = av.z; a3 = av.w;
        }
        const float area = (a2 - a0) * (a3 - a1);

        int rkey = -1;
        const int akey = active ? (4095 - a) : -1;   // -1 disables ckey contribution sign? keep 0 path below
        #pragma unroll
        for (int g = 0; g < NGT; ++g) {
            const float4 g4 = gtp[g];                // uniform -> s_load
            const float area_g = (g4.z - g4.x) * (g4.w - g4.y);
            float ih = fmaxf(fminf(a2, g4.z) - fmaxf(a0, g4.x), 0.0f);
            float iw = fmaxf(fminf(a3, g4.w) - fmaxf(a1, g4.y), 0.0f);
            float inter = ih * iw;
            float uni = area + area_g - inter;       // same assoc order as numpy
            float iou = inter / (uni + EPSF);        // IEEE div (no fast-math)
            int v = (int)(iou * 10000.0f);           // trunc == astype(int32)
            int rk = (v << 5) | (31 - g);            // max => max v, tie -> first g
            rkey = max(rkey, rk);
            int key = active ? ((v << 12) | (4095 - a)) : 0; // tie -> min a
            ckey[g] = max(ckey[g], key);
        }
        if (active) {
            pack[(size_t)b * n_ac + a] = rkey;
            const int vmax = rkey >> 5;
            cf += (vmax >= 5000);
            cb += (vmax < 3000);
        }
    }

    // column-key wave reduce (once per APT anchors), then block reduce + atomic
    #pragma unroll
    for (int g = 0; g < NGT; ++g) {
        int k = ckey[g];
        #pragma unroll
        for (int off = 32; off >= 1; off >>= 1)
            k = max(k, __shfl_xor(k, off, 64));
        if (lane == 0) s_wk[g*4 + w] = k;
    }

    #pragma unroll
    for (int off = 32; off >= 1; off >>= 1) {
        cf += __shfl_xor(cf, off, 64);
        cb += __shfl_xor(cb, off, 64);
    }
    if (lane == 0) { s_c[w*2] = cf; s_c[w*2+1] = cb; }
    __syncthreads();

    if (tid < NGT) {
        int k = max(max(s_wk[tid*4+0], s_wk[tid*4+1]),
                    max(s_wk[tid*4+2], s_wk[tid*4+3]));
        atomicMax(&colkey[b * NGT + tid], k);   // signed: 0xAAAAAAAA poison loses
    }
    if (tid == 0) {
        partial[(b * gridDim.x + chunk) * 2 + 0] = s_c[0] + s_c[2] + s_c[4] + s_c[6];
        partial[(b * gridDim.x + chunk) * 2 + 1] = s_c[1] + s_c[3] + s_c[5] + s_c[7];
    }
}

// ---------------- Kernel 2: finalize counts, mark gtac anchors, thresholds ----
__global__ __launch_bounds__(64) void rpn_k2(
    int* __restrict__ pack,
    const int* __restrict__ colkey,
    const int* __restrict__ partial,
    float* __restrict__ th,            // (B, 2)
    int n_ac, int n_chunk)
{
    const int b = blockIdx.x, tid = threadIdx.x;   // one wave per batch row

    int pf = 0, pb = 0;
    if (tid < n_chunk) {
        pf = partial[(b * n_chunk + tid) * 2 + 0];
        pb = partial[(b * n_chunk + tid) * 2 + 1];
    }
    #pragma unroll
    for (int off = 32; off >= 1; off >>= 1) {
        pf += __shfl_xor(pf, off, 64);
        pb += __shfl_xor(pb, off, 64);
    }

    int valid = 0, a = 0;
    if (tid < NGT) {
        int key = colkey[b * NGT + tid];
        int v = key >> 12;
        a = 4095 - (key & 4095);
        valid = (v >= 100);               // POS_TH_GTAC
    }
    // dedupe: count each distinct gtac anchor once (first occurrence)
    int av = valid ? a : (0x10000 + tid);
    bool dup = false;
    for (int gp = 0; gp < NGT; ++gp) {
        int o = __shfl(av, gp, 64);
        if (gp < tid && o == av) dup = true;
    }
    bool contrib = valid && !dup;
    int rm = 0x7FFF;
    if (contrib) rm = pack[(size_t)b * n_ac + a] >> 5;  // distinct a per lane: no race
    unsigned long long m1 = __ballot(contrib && rm < 5000); // gtac-only positives
    unsigned long long m2 = __ballot(contrib && rm < 3000); // neg -> pos corrections

    if (contrib) atomicOr(&pack[(size_t)b * n_ac + a], GTAC_BIT);

    if (tid == 0) {
        int cf = pf + __popcll(m1);
        int cb = pb - __popcll(m2);
        th[b*2 + 0] = 128.0f / ((float)cf + 1e-6f);
        th[b*2 + 1] = 128.0f / ((float)cb + 1e-6f);
    }
}

// ---------------- Kernel 3: per-anchor epilogue + coalesced output write ------
__global__ __launch_bounds__(256) void rpn_k3(
    const float* __restrict__ bx_gt,
    const float* __restrict__ ac_val,
    const float* __restrict__ rand_pos,
    const float* __restrict__ rand_neg,
    const int* __restrict__ pack,
    const float* __restrict__ th,
    float* __restrict__ out,           // (B, n_ac, 10)
    int n_ac)
{
    #pragma clang fp contract(off)
    const int b = blockIdx.y, chunk = blockIdx.x, tid = threadIdx.x;

    __shared__ float s_gt[NGT * 4];
    __shared__ float s_o[10 * 257];    // [k][a_local] padded: <=2-way banks both ways

    if (tid < NGT * 4) s_gt[tid] = bx_gt[(size_t)b * NGT * 4 + tid];
    __syncthreads();

    const int a = chunk * 256 + tid;
    if (a < n_ac) {
        const float th_pos = th[b*2 + 0];
        const float th_neg = th[b*2 + 1];
        const int p = pack[(size_t)b * n_ac + a];
        const bool gtac = (p & GTAC_BIT) != 0;
        const int rm = (p >> 5) & 0x7FFF;
        const int bg = 31 - (p & 31);
        const bool pos = (rm >= 5000) || gtac;
        const bool neg = !pos && (rm < 3000);

        const float4 avv = ((const float4*)ac_val)[a];
        const float a0 = avv.x, a1 = avv.y, a2 = avv.z, a3 = avv.w;

        float o0, o1, o2, o3, o4, o5, o6, o7;
        if (pos) {
            float g0 = s_gt[bg*4+0], g1 = s_gt[bg*4+1];
            float g2 = s_gt[bg*4+2], g3 = s_gt[bg*4+3];
            o0 = g0; o1 = g1; o2 = g2; o3 = g3;
            float hr = fmaxf(a2 - a0, EPSF);
            float wr = fmaxf(a3 - a1, EPSF);
            float ycr = a0 + 0.5f * (a2 - a0);
            float xcr = a1 + 0.5f * (a3 - a1);
            float hl = g2 - g0, wl = g3 - g1;
            float ycl = g0 + 0.5f * hl;
            float xcl = g1 + 0.5f * wl;
            o4 = fminf(fmaxf((xcl - xcr) / wr, -10.0f), 10.0f);
            o5 = fminf(fmaxf((ycl - ycr) / hr, -10.0f), 10.0f);
            o6 = fminf(fmaxf(logf(wl / wr), -10.0f), 10.0f);
            o7 = fminf(fmaxf(logf(hl / hr), -10.0f), 10.0f);
        } else {
            float t = neg ? -2.0f : -1.0f;
            o0 = o1 = o2 = o3 = t;
            o4 = o5 = o6 = o7 = 0.0f;   // bx_safe == anchor => delta exactly 0
        }
        const float o8 = (pos && rand_pos[(size_t)b * n_ac + a] < th_pos) ? 1.0f : 0.0f;
        const float o9 = (neg && rand_neg[(size_t)b * n_ac + a] < th_neg) ? 1.0f : 0.0f;

        s_o[0*257 + tid] = o0; s_o[1*257 + tid] = o1;
        s_o[2*257 + tid] = o2; s_o[3*257 + tid] = o3;
        s_o[4*257 + tid] = o4; s_o[5*257 + tid] = o5;
        s_o[6*257 + tid] = o6; s_o[7*257 + tid] = o7;
        s_o[8*257 + tid] = o8; s_o[9*257 + tid] = o9;
    }
    __syncthreads();

    // coalesced write: block's dword range is [(b*n_ac + chunk*256)*10, +nd*10)
    const int na_blk = min(256, n_ac - chunk * 256);
    const int nd = na_blk * 10;
    float* dst = out + ((size_t)b * n_ac + (size_t)chunk * 256) * 10;
    #pragma unroll
    for (int m = 0; m < 10; ++m) {
        const int idx = m * 256 + tid;
        if (idx < nd) {
            const int al = idx / 10, k = idx - al * 10;
            dst[idx] = s_o[k * 257 + al];
        }
    }
}

extern "C" void kernel_launch(void* const* d_in, const int* in_sizes, int n_in,
                              void* d_out, int out_size, void* d_ws, size_t ws_size,
                              hipStream_t stream) {
    const float* bx_gt    = (const float*)d_in[0];
    const float* ac_val   = (const float*)d_in[1];
    const float* rand_pos = (const float*)d_in[2];
    const float* rand_neg = (const float*)d_in[3];
    float* out = (float*)d_out;

    const int n_ac     = in_sizes[1] / 4;     // (n_ac, 4)
    const int B        = in_sizes[2] / n_ac;  // rand_pos is (B, n_ac)
    const int n_chunk1 = (n_ac + K1SPAN - 1) / K1SPAN;
    const int n_chunk3 = (n_ac + 255) / 256;

    // ws layout (ints): pack[B*n_ac] | colkey[B*32] | partial[B*n_chunk1*2] | th (floats, B*2)
    int* pack    = (int*)d_ws;
    int* colkey  = pack + (size_t)B * n_ac;
    int* partial = colkey + (size_t)B * NGT;
    float* th    = (float*)(partial + (size_t)B * n_chunk1 * 2);

    rpn_k1<<<dim3(n_chunk1, B), 256, 0, stream>>>(bx_gt, ac_val, pack, colkey, partial, n_ac);
    rpn_k2<<<B, 64, 0, stream>>>(pack, colkey, partial, th, n_ac, n_chunk1);
    rpn_k3<<<dim3(n_chunk3, B), 256, 0, stream>>>(bx_gt, ac_val, rand_pos, rand_neg,
                                                  pack, th, out, n_ac);
}